// Round 9
// baseline (37.917 us; speedup 1.0000x reference)
//
#include <hip/hip_runtime.h>
#include <hip/hip_bf16.h>
#include <cstdint>

#define K_DIM 1024
#define N_DIM 128
#define BM 64
#define NGT 32           // global K-tiles of 32
#define D_PF 5           // A prefetch distance (tiles); ring-6

typedef __attribute__((ext_vector_type(8))) short bf16x8;
typedef __attribute__((ext_vector_type(4))) float f32x4;
typedef unsigned short u16;
typedef unsigned int u32;

__device__ __forceinline__ float pwbq(float w) {
  w = fminf(fmaxf(w, -1.0f), 1.0f);
  return rintf(w * 127.0f) * (1.0f / 127.0f);
}

// float -> bf16 round-to-nearest-even (finite inputs only)
__device__ __forceinline__ u16 f2bf(float f) {
  union { float f; u32 u; } v; v.f = f;
  u32 r = v.u + 0x7FFFu + ((v.u >> 16) & 1u);
  return (u16)(r >> 16);
}

// Wimg[t][col][j] : [32][128][32] bf16 = quantize(W[(t*32+j)*128 + col]).
// Read-coalesced: thread e reads W[e] (contiguous), scatters the 2B write.
__global__ __launch_bounds__(256) void quantW_kernel(const float* __restrict__ W,
                                                     u16* __restrict__ Wimg) {
  int e = blockIdx.x * 256 + threadIdx.x;   // 0 .. 131071
  int k = e >> 7;                           // row of W
  int col = e & 127;
  Wimg[(k >> 5) * 4096 + col * 32 + (k & 31)] = f2bf(pwbq(W[e]));
}

// Correctness-insurance fallback (only if d_ws is unusably small).
__global__ __launch_bounds__(256) void naive_kernel(const float* __restrict__ x,
                                                    const float* __restrict__ W,
                                                    const float* __restrict__ b,
                                                    float* __restrict__ out, int total) {
  int idx = blockIdx.x * 256 + threadIdx.x;
  if (idx >= total) return;
  int m = idx >> 7, n = idx & 127;
  float acc = pwbq(b[n]);
  for (int k = 0; k < K_DIM; ++k)
    acc = fmaf(x[(size_t)m * K_DIM + k], pwbq(W[k * N_DIM + n]), acc);
  out[idx] = acc;
}

// out[M][128] = x[M][1024] @ Wq + bq
// 256 thr / 4 waves; each wave owns 16 rows x ALL 128 cols (no A sharing).
// B: one K-quarter [8][128][32] bf16 = 64 KB LDS (16 chunks/thread), staged
//    in-place 4x per block -> 7 barriers total; 8 sync-free K-tiles between.
// A: global->reg ring-6, distance-5 prefetch (~1000cyc > HBM latency), full
//    unroll -> static indices; compiler emits exact per-load waitcnts.
// Boundary: lgkmcnt(0) -> barrier -> stageB -> vmcnt(0) -> barrier.
__global__ __launch_bounds__(256, 2) void pwb_gemm(
    const float* __restrict__ x,
    const u16* __restrict__ Wimg,
    const float* __restrict__ bias,
    float* __restrict__ out) {

  __shared__ __align__(16) u16 Bq[8 * N_DIM * 32];   // 64 KB, one K-quarter

  const int tid  = threadIdx.x;
  const int lane = tid & 63;
  const int wid  = tid >> 6;      // 0..3 : 16-row group
  const int l15  = lane & 15;
  const int lg   = lane >> 4;     // 0..3 : k-group (k = lg*8 + j)

  const int rowA = blockIdx.x * BM + wid * 16 + l15;        // A-frag row
  const float* xr = x + (size_t)rowA * K_DIM + lg * 8;      // per-lane A base

  // Stage K-quarter q of Wimg (64 KB contiguous) linearly into LDS.
  // 16 chunks/thread x 256 threads x 16B = 64 KB (full quarter).
  auto stageB = [&](int q) {
    const u16* src = Wimg + (size_t)q * (8 * 4096);
#pragma unroll
    for (int i = 0; i < 16; ++i) {
      int cd = i * 256 + tid;
      __builtin_amdgcn_global_load_lds(
          (const __attribute__((address_space(1))) void*)(src + cd * 8),
          (__attribute__((address_space(3))) void*)(&Bq[cd * 8]), 16, 0, 0);
    }
  };

  f32x4 ar[6][2];   // ring-6 A register file (slot = g % 6, static after unroll)
#define LOADA(G)                                             \
  do {                                                       \
    ar[(G) % 6][0] = *(const f32x4*)(xr + (G) * 32);         \
    ar[(G) % 6][1] = *(const f32x4*)(xr + (G) * 32 + 4);     \
  } while (0)

  f32x4 acc[8] = {};

  // Prologue: stage quarter 0, drain it (reorder-proof), then warm the A ring.
  stageB(0);
  asm volatile("s_waitcnt vmcnt(0)" ::: "memory");
#pragma unroll
  for (int g0 = 0; g0 < D_PF; ++g0) LOADA(g0);
  asm volatile("s_barrier" ::: "memory");   // Bq(0) visible to all waves

#pragma unroll
  for (int q = 0; q < 4; ++q) {
#pragma unroll
    for (int i = 0; i < 8; ++i) {
      const int g = q * 8 + i;           // global K-tile index

      if (g + D_PF < NGT) LOADA(g + D_PF);

      // ---- compute tile g (compiler auto-waits the A-load registers) ----
      union { bf16x8 v; __hip_bfloat162 p[4]; } pa;
      f32x4 r0 = ar[g % 6][0];
      f32x4 r1 = ar[g % 6][1];
      pa.p[0] = __float22bfloat162_rn(make_float2(r0[0], r0[1]));
      pa.p[1] = __float22bfloat162_rn(make_float2(r0[2], r0[3]));
      pa.p[2] = __float22bfloat162_rn(make_float2(r1[0], r1[1]));
      pa.p[3] = __float22bfloat162_rn(make_float2(r1[2], r1[3]));
      bf16x8 a = pa.v;

      const u16* Bb = &Bq[(g & 7) * 4096];
#pragma unroll
      for (int f = 0; f < 8; ++f) {
        bf16x8 bfr = *(const bf16x8*)(Bb + (f * 16 + l15) * 32 + lg * 8);
        acc[f] = __builtin_amdgcn_mfma_f32_16x16x32_bf16(a, bfr, acc[f], 0, 0, 0);
      }

      // ---- quarter boundary: in-place restage of Bq ----
      if (i == 7 && q < 3) {
        // Drain this wave's LDS reads before anyone overwrites Bq (raw
        // s_barrier does NOT wait lgkmcnt; rule #18 fence included).
        asm volatile("s_waitcnt lgkmcnt(0)" ::: "memory");
        __builtin_amdgcn_sched_barrier(0);
        asm volatile("s_barrier" ::: "memory");   // all waves done reading q
        stageB(q + 1);                            // 16 vmem insts
        asm volatile("s_waitcnt vmcnt(0)" ::: "memory");  // stage landed
        asm volatile("s_barrier" ::: "memory");   // Bq(q+1) visible to all
      }
    }
  }
#undef LOADA

  // epilogue: C/D layout col=lane&15, row=(lane>>4)*4+j
  const int orow0 = blockIdx.x * BM + wid * 16 + lg * 4;
#pragma unroll
  for (int f = 0; f < 8; ++f) {
    const int gc = f * 16 + l15;
    const float bq = pwbq(bias[gc]);
#pragma unroll
    for (int j = 0; j < 4; ++j)
      out[(size_t)(orow0 + j) * N_DIM + gc] = acc[f][j] + bq;
  }
}

extern "C" void kernel_launch(void* const* d_in, const int* in_sizes, int n_in,
                              void* d_out, int out_size, void* d_ws, size_t ws_size,
                              hipStream_t stream) {
  const float* x = (const float*)d_in[0];
  const float* W = (const float*)d_in[1];
  const float* b = (const float*)d_in[2];
  float* out = (float*)d_out;

  const int M = in_sizes[0] / K_DIM;   // 32768
  const int grid = M / BM;             // 512

  const size_t need = (size_t)K_DIM * N_DIM * sizeof(u16);  // 256 KiB
  if (d_ws != nullptr && ws_size >= need) {
    u16* Wimg = (u16*)d_ws;
    quantW_kernel<<<(K_DIM * N_DIM) / 256, 256, 0, stream>>>(W, Wimg);
    pwb_gemm<<<grid, 256, 0, stream>>>(x, Wimg, b, out);
  } else {
    int total = M * N_DIM;
    naive_kernel<<<(total + 255) / 256, 256, 0, stream>>>(x, W, b, out, total);
  }
}

// Round 10
// 32.410 us; speedup vs baseline: 1.1699x; 1.1699x over previous
//
#include <hip/hip_runtime.h>
#include <hip/hip_bf16.h>
#include <cstdint>

#define K_DIM 1024
#define N_DIM 128
#define BM 64
#define BK 32
#define NT 32            // K-tiles of 32

typedef __attribute__((ext_vector_type(8))) short bf16x8;
typedef __attribute__((ext_vector_type(4))) short bf16x4;
typedef __attribute__((ext_vector_type(4))) float f32x4;
typedef unsigned short u16;
typedef unsigned int u32;

__device__ __forceinline__ float pwbq(float w) {
  w = fminf(fmaxf(w, -1.0f), 1.0f);
  return rintf(w * 127.0f) * (1.0f / 127.0f);
}

// float -> bf16 round-to-nearest-even (finite inputs only)
__device__ __forceinline__ u16 f2bf(float f) {
  union { float f; u32 u; } v; v.f = f;
  u32 r = v.u + 0x7FFFu + ((v.u >> 16) & 1u);
  return (u16)(r >> 16);
}

// Wimg chunk layout per K-tile t: halves index = t*4096 + (kq*128 + col)*8 + j
// holding quantize(W[t*32 + kq*8 + j][col]); kq = k-octet 0..3. This is the
// exact linear LDS image for gload_lds; fragment read = chunk (lg*128 + col).
__global__ __launch_bounds__(256) void quantW_kernel(const float* __restrict__ W,
                                                     u16* __restrict__ Wimg) {
  int e = blockIdx.x * 256 + threadIdx.x;   // 0 .. 131071 (coalesced W read)
  int k = e >> 7;
  int col = e & 127;
  int t = k >> 5, kq = (k >> 3) & 3, j = k & 7;
  Wimg[t * 4096 + (kq * 128 + col) * 8 + j] = f2bf(pwbq(W[e]));
}

// Correctness-insurance fallback (only if d_ws is unusably small).
__global__ __launch_bounds__(256) void naive_kernel(const float* __restrict__ x,
                                                    const float* __restrict__ W,
                                                    const float* __restrict__ b,
                                                    float* __restrict__ out, int total) {
  int idx = blockIdx.x * 256 + threadIdx.x;
  if (idx >= total) return;
  int m = idx >> 7, n = idx & 127;
  float acc = pwbq(b[n]);
  for (int k = 0; k < K_DIM; ++k)
    acc = fmaf(x[(size_t)m * K_DIM + k], pwbq(W[k * N_DIM + n]), acc);
  out[idx] = acc;
}

// out[M][128] = x[M][1024] @ Wq + bq
// 512 thr / 8 waves (2 row-groups x 4 col-groups), wave tile 32x32 (square ->
// minimal LDS read amplification: 44 KB/tile/block, ~13us/CU total).
// A: per-thread f32x4 -> cvt_pk bf16 -> ds_write_b64 (uniform 1 vmem/thread).
// B: global_load_lds 16B from fragment-ordered Wimg (uniform 1 vmem/thread).
// Rings: A regs ring-3 depth-3, A LDS ring-3, B LDS ring-3 depth-2.
// Per iter: vmcnt(2) [retires B(t)+A(t+1) exactly] -> WRITEA(t+1) ->
// lgkmcnt(0) -> sched_barrier -> s_barrier -> LOADA(t+3),ISSUEB(t+2) ->
// compute(t). Stage-after-barrier => in-place slot reuse is race-free.
__global__ __launch_bounds__(512, 4) void pwb_gemm(
    const float* __restrict__ x,
    const u16* __restrict__ Wimg,
    const float* __restrict__ bias,
    float* __restrict__ out) {

  __shared__ __align__(16) u16 Al[3][BM * BK];     // 3 x 4 KB bf16
  __shared__ __align__(16) u16 Bl[3][N_DIM * BK];  // 3 x 8 KB bf16

  const int tid  = threadIdx.x;
  const int lane = tid & 63;
  const int wid  = tid >> 6;   // 0..7
  const int wr   = wid >> 2;   // 0..1 : 32-row group
  const int wc   = wid & 3;    // 0..3 : 32-col group
  const int m0   = blockIdx.x * BM;
  const int l15  = lane & 15;
  const int lg   = lane >> 4;  // 0..3 : k-octet (k = lg*8 + j)

  // A staging: thread -> (row grow, k-quad q8); 512 thr x 4 floats = 64x32.
  const int grow = tid >> 3;   // 0..63
  const int q8   = tid & 7;    // 0..7
  const float* asrc = x + (size_t)(m0 + grow) * K_DIM + q8 * 4;
  const int aoff = ((q8 >> 1) * 64 + grow) * 8 + (q8 & 1) * 4;  // halves

  f32x4 areg[3];   // reg ring-3 (static indices after full unroll)

#define LOADA(G) do { areg[(G) % 3] = *(const f32x4*)(asrc + (G) * BK); } while (0)

#define WRITEA(G)                                                        \
  do {                                                                   \
    f32x4 r = areg[(G) % 3];                                             \
    union { bf16x4 v; __hip_bfloat162 p[2]; } pa;                        \
    pa.p[0] = __float22bfloat162_rn(make_float2(r[0], r[1]));            \
    pa.p[1] = __float22bfloat162_rn(make_float2(r[2], r[3]));            \
    *(bf16x4*)(&Al[(G) % 3][aoff]) = pa.v;                               \
  } while (0)

#define ISSUEB(T)                                                        \
  do {                                                                   \
    const u16* srcB = Wimg + (size_t)(T) * 4096 + tid * 8;               \
    __builtin_amdgcn_global_load_lds(                                    \
        (const __attribute__((address_space(1))) void*)srcB,             \
        (__attribute__((address_space(3))) void*)(&Bl[(T) % 3][tid * 8]),\
        16, 0, 0);                                                       \
  } while (0)

  f32x4 acc[2][2] = {};

  // Prologue. Issue order: A0,A1,B0,A2,B1 (5 outstanding).
  // vmcnt(4) retires A0 only; invariant entering t=0: [A1,B0,A2,B1].
  LOADA(0);
  LOADA(1);
  ISSUEB(0);
  LOADA(2);
  ISSUEB(1);
  asm volatile("s_waitcnt vmcnt(4)" ::: "memory");
  WRITEA(0);

#pragma unroll
  for (int t = 0; t < NT; ++t) {
    // Entering outstanding (oldest first): [A(t+1), B(t), A(t+2), B(t+1)].
    // vmcnt(2) retires exactly B(t) (LDS valid) + A(t+1) (regs valid).
    if (t <= NT - 3)      asm volatile("s_waitcnt vmcnt(2)" ::: "memory");
    else if (t == NT - 2) asm volatile("s_waitcnt vmcnt(1)" ::: "memory");
    else                  asm volatile("s_waitcnt vmcnt(0)" ::: "memory");

    if (t + 1 < NT) {
      WRITEA(t + 1);                                   // -> Al[(t+1)%3]
      asm volatile("s_waitcnt lgkmcnt(0)" ::: "memory");
    }
    __builtin_amdgcn_sched_barrier(0);
    asm volatile("s_barrier" ::: "memory");

    // Stage issue AFTER the barrier: B target slot (t+2)%3 == (t-1)%3, whose
    // readers (compute(t-1)) all drained their ds_reads before this barrier.
    if (t + 3 < NT) LOADA(t + 3);
    if (t + 2 < NT) ISSUEB(t + 2);

    // ---- compute tile t: 4 ds_read_b128 + 4 MFMA ----
    const u16* Ab = &Al[t % 3][0];
    const u16* Bb = &Bl[t % 3][0];
    bf16x8 a[2], b[2];
#pragma unroll
    for (int q = 0; q < 2; ++q)
      a[q] = *(const bf16x8*)(Ab + (lg * 64 + wr * 32 + q * 16 + l15) * 8);
#pragma unroll
    for (int f = 0; f < 2; ++f)
      b[f] = *(const bf16x8*)(Bb + (lg * 128 + wc * 32 + f * 16 + l15) * 8);
#pragma unroll
    for (int q = 0; q < 2; ++q)
#pragma unroll
      for (int f = 0; f < 2; ++f)
        acc[q][f] = __builtin_amdgcn_mfma_f32_16x16x32_bf16(a[q], b[f], acc[q][f], 0, 0, 0);
  }
#undef LOADA
#undef WRITEA
#undef ISSUEB

  // epilogue: C/D layout col=lane&15, row=(lane>>4)*4+j (verified r4/5/7)
#pragma unroll
  for (int q = 0; q < 2; ++q) {
    const int gr0 = m0 + wr * 32 + q * 16 + lg * 4;
#pragma unroll
    for (int f = 0; f < 2; ++f) {
      const int gc = wc * 32 + f * 16 + l15;
      const float bq = pwbq(bias[gc]);
#pragma unroll
      for (int j = 0; j < 4; ++j)
        out[(size_t)(gr0 + j) * N_DIM + gc] = acc[q][f][j] + bq;
    }
  }
}

extern "C" void kernel_launch(void* const* d_in, const int* in_sizes, int n_in,
                              void* d_out, int out_size, void* d_ws, size_t ws_size,
                              hipStream_t stream) {
  const float* x = (const float*)d_in[0];
  const float* W = (const float*)d_in[1];
  const float* b = (const float*)d_in[2];
  float* out = (float*)d_out;

  const int M = in_sizes[0] / K_DIM;   // 32768
  const int grid = M / BM;             // 512

  const size_t need = (size_t)K_DIM * N_DIM * sizeof(u16);  // 256 KiB
  if (d_ws != nullptr && ws_size >= need) {
    u16* Wimg = (u16*)d_ws;
    quantW_kernel<<<(K_DIM * N_DIM) / 256, 256, 0, stream>>>(W, Wimg);
    pwb_gemm<<<grid, 512, 0, stream>>>(x, Wimg, b, out);
  } else {
    int total = M * N_DIM;
    naive_kernel<<<(total + 255) / 256, 256, 0, stream>>>(x, W, b, out, total);
  }
}

// Round 11
// 32.349 us; speedup vs baseline: 1.1721x; 1.0019x over previous
//
#include <hip/hip_runtime.h>
#include <hip/hip_bf16.h>
#include <cstdint>

#define K_DIM 1024
#define N_DIM 128
#define BM 64
#define BK 32
#define NT 32            // K-tiles of 32

typedef __attribute__((ext_vector_type(8))) short bf16x8;
typedef __attribute__((ext_vector_type(4))) short bf16x4;
typedef __attribute__((ext_vector_type(4))) float f32x4;
typedef unsigned short u16;
typedef unsigned int u32;

__device__ __forceinline__ float pwbq(float w) {
  w = fminf(fmaxf(w, -1.0f), 1.0f);
  return rintf(w * 127.0f) * (1.0f / 127.0f);
}

// float -> bf16 round-to-nearest-even (finite inputs only)
__device__ __forceinline__ u16 f2bf(float f) {
  union { float f; u32 u; } v; v.f = f;
  u32 r = v.u + 0x7FFFu + ((v.u >> 16) & 1u);
  return (u16)(r >> 16);
}

// Wimg chunk layout per K-tile t: halves index = t*4096 + (kq*128 + col)*8 + j
// holding quantize(W[t*32 + kq*8 + j][col]); kq = k-octet 0..3. This is the
// exact linear LDS image for gload_lds; fragment read = chunk (lg*128 + col).
__global__ __launch_bounds__(256) void quantW_kernel(const float* __restrict__ W,
                                                     u16* __restrict__ Wimg) {
  int e = blockIdx.x * 256 + threadIdx.x;   // 0 .. 131071 (coalesced W read)
  int k = e >> 7;
  int col = e & 127;
  int t = k >> 5, kq = (k >> 3) & 3, j = k & 7;
  Wimg[t * 4096 + (kq * 128 + col) * 8 + j] = f2bf(pwbq(W[e]));
}

// Correctness-insurance fallback (only if d_ws is unusably small).
__global__ __launch_bounds__(256) void naive_kernel(const float* __restrict__ x,
                                                    const float* __restrict__ W,
                                                    const float* __restrict__ b,
                                                    float* __restrict__ out, int total) {
  int idx = blockIdx.x * 256 + threadIdx.x;
  if (idx >= total) return;
  int m = idx >> 7, n = idx & 127;
  float acc = pwbq(b[n]);
  for (int k = 0; k < K_DIM; ++k)
    acc = fmaf(x[(size_t)m * K_DIM + k], pwbq(W[k * N_DIM + n]), acc);
  out[idx] = acc;
}

// out[M][128] = x[M][1024] @ Wq + bq
// 512 thr / 8 waves (2 row-groups x 4 col-groups), wave tile 32x32 (square ->
// minimal LDS read amplification: 44 KB/tile/block, ~13us/CU total).
// A: per-thread f32x4 -> cvt_pk bf16 -> ds_write_b64 (uniform 1 vmem/thread).
// B: global_load_lds 16B from fragment-ordered Wimg (uniform 1 vmem/thread).
// Rings: A regs ring-3 depth-3, A LDS ring-3, B LDS ring-3 depth-2.
// Per iter: vmcnt(2) [retires B(t)+A(t+1) exactly] -> WRITEA(t+1) ->
// lgkmcnt(0) -> sched_barrier -> s_barrier -> LOADA(t+3),ISSUEB(t+2) ->
// compute(t). Stage-after-barrier => in-place slot reuse is race-free.
__global__ __launch_bounds__(512, 4) void pwb_gemm(
    const float* __restrict__ x,
    const u16* __restrict__ Wimg,
    const float* __restrict__ bias,
    float* __restrict__ out) {

  __shared__ __align__(16) u16 Al[3][BM * BK];     // 3 x 4 KB bf16
  __shared__ __align__(16) u16 Bl[3][N_DIM * BK];  // 3 x 8 KB bf16

  const int tid  = threadIdx.x;
  const int lane = tid & 63;
  const int wid  = tid >> 6;   // 0..7
  const int wr   = wid >> 2;   // 0..1 : 32-row group
  const int wc   = wid & 3;    // 0..3 : 32-col group
  const int m0   = blockIdx.x * BM;
  const int l15  = lane & 15;
  const int lg   = lane >> 4;  // 0..3 : k-octet (k = lg*8 + j)

  // A staging: thread -> (row grow, k-quad q8); 512 thr x 4 floats = 64x32.
  const int grow = tid >> 3;   // 0..63
  const int q8   = tid & 7;    // 0..7
  const float* asrc = x + (size_t)(m0 + grow) * K_DIM + q8 * 4;
  const int aoff = ((q8 >> 1) * 64 + grow) * 8 + (q8 & 1) * 4;  // halves

  f32x4 areg[3];   // reg ring-3 (static indices after full unroll)

#define LOADA(G) do { areg[(G) % 3] = *(const f32x4*)(asrc + (G) * BK); } while (0)

#define WRITEA(G)                                                        \
  do {                                                                   \
    f32x4 r = areg[(G) % 3];                                             \
    union { bf16x4 v; __hip_bfloat162 p[2]; } pa;                        \
    pa.p[0] = __float22bfloat162_rn(make_float2(r[0], r[1]));            \
    pa.p[1] = __float22bfloat162_rn(make_float2(r[2], r[3]));            \
    *(bf16x4*)(&Al[(G) % 3][aoff]) = pa.v;                               \
  } while (0)

#define ISSUEB(T)                                                        \
  do {                                                                   \
    const u16* srcB = Wimg + (size_t)(T) * 4096 + tid * 8;               \
    __builtin_amdgcn_global_load_lds(                                    \
        (const __attribute__((address_space(1))) void*)srcB,             \
        (__attribute__((address_space(3))) void*)(&Bl[(T) % 3][tid * 8]),\
        16, 0, 0);                                                       \
  } while (0)

  f32x4 acc[2][2] = {};

  // Prologue. Issue order: A0,A1,B0,A2,B1 (5 outstanding).
  // vmcnt(4) retires A0 only; invariant entering t=0: [A1,B0,A2,B1].
  LOADA(0);
  LOADA(1);
  ISSUEB(0);
  LOADA(2);
  ISSUEB(1);
  asm volatile("s_waitcnt vmcnt(4)" ::: "memory");
  WRITEA(0);

#pragma unroll
  for (int t = 0; t < NT; ++t) {
    // Entering outstanding (oldest first): [A(t+1), B(t), A(t+2), B(t+1)].
    // vmcnt(2) retires exactly B(t) (LDS valid) + A(t+1) (regs valid).
    if (t <= NT - 3)      asm volatile("s_waitcnt vmcnt(2)" ::: "memory");
    else if (t == NT - 2) asm volatile("s_waitcnt vmcnt(1)" ::: "memory");
    else                  asm volatile("s_waitcnt vmcnt(0)" ::: "memory");

    if (t + 1 < NT) {
      WRITEA(t + 1);                                   // -> Al[(t+1)%3]
      asm volatile("s_waitcnt lgkmcnt(0)" ::: "memory");
    }
    __builtin_amdgcn_sched_barrier(0);
    asm volatile("s_barrier" ::: "memory");

    // Stage issue AFTER the barrier: B target slot (t+2)%3 == (t-1)%3, whose
    // readers (compute(t-1)) all drained their ds_reads before this barrier.
    if (t + 3 < NT) LOADA(t + 3);
    if (t + 2 < NT) ISSUEB(t + 2);

    // ---- compute tile t: 4 ds_read_b128 + 4 MFMA ----
    const u16* Ab = &Al[t % 3][0];
    const u16* Bb = &Bl[t % 3][0];
    bf16x8 a[2], b[2];
#pragma unroll
    for (int q = 0; q < 2; ++q)
      a[q] = *(const bf16x8*)(Ab + (lg * 64 + wr * 32 + q * 16 + l15) * 8);
#pragma unroll
    for (int f = 0; f < 2; ++f)
      b[f] = *(const bf16x8*)(Bb + (lg * 128 + wc * 32 + f * 16 + l15) * 8);
#pragma unroll
    for (int q = 0; q < 2; ++q)
#pragma unroll
      for (int f = 0; f < 2; ++f)
        acc[q][f] = __builtin_amdgcn_mfma_f32_16x16x32_bf16(a[q], b[f], acc[q][f], 0, 0, 0);
  }
#undef LOADA
#undef WRITEA
#undef ISSUEB

  // epilogue: C/D layout col=lane&15, row=(lane>>4)*4+j (verified r4/5/7)
#pragma unroll
  for (int q = 0; q < 2; ++q) {
    const int gr0 = m0 + wr * 32 + q * 16 + lg * 4;
#pragma unroll
    for (int f = 0; f < 2; ++f) {
      const int gc = wc * 32 + f * 16 + l15;
      const float bq = pwbq(bias[gc]);
#pragma unroll
      for (int j = 0; j < 4; ++j)
        out[(size_t)(gr0 + j) * N_DIM + gc] = acc[q][f][j] + bq;
    }
  }
}

extern "C" void kernel_launch(void* const* d_in, const int* in_sizes, int n_in,
                              void* d_out, int out_size, void* d_ws, size_t ws_size,
                              hipStream_t stream) {
  const float* x = (const float*)d_in[0];
  const float* W = (const float*)d_in[1];
  const float* b = (const float*)d_in[2];
  float* out = (float*)d_out;

  const int M = in_sizes[0] / K_DIM;   // 32768
  const int grid = M / BM;             // 512

  const size_t need = (size_t)K_DIM * N_DIM * sizeof(u16);  // 256 KiB
  if (d_ws != nullptr && ws_size >= need) {
    u16* Wimg = (u16*)d_ws;
    quantW_kernel<<<(K_DIM * N_DIM) / 256, 256, 0, stream>>>(W, Wimg);
    pwb_gemm<<<grid, 512, 0, stream>>>(x, Wimg, b, out);
  } else {
    int total = M * N_DIM;
    naive_kernel<<<(total + 255) / 256, 256, 0, stream>>>(x, W, b, out, total);
  }
}